// Round 1
// baseline (125.450 us; speedup 1.0000x reference)
//
#include <hip/hip_runtime.h>
#include <hip/hip_bf16.h>

#define D 128
#define TILE_R 128   // rows of EMBEDM per block in the precompute GEMM

// ---------------------------------------------------------------------------
// Phase 1: E' = EMBEDM @ metric   (nrows x 128) @ (128 x 128) -> d_ws
// 256 threads/block, TILE_R rows per block.
// LDS: full metric (64 KB) + E tile (64 KB) = 128 KB (gfx950 has 160 KB/CU).
// Thread (cg, rg): cg = tid&31 -> 4 output cols e0=cg*4; rg = tid>>5 -> 16 rows.
// Register tile 16x4, inner loop over d in steps of 4:
//   20 ds_read_b128 per 256 FMA.
// ---------------------------------------------------------------------------
__global__ __launch_bounds__(256) void precompute_EM(
    const float* __restrict__ E, const float* __restrict__ M,
    float* __restrict__ Eo, int nrows)
{
    __shared__ float sM[D * D];       // 64 KB
    __shared__ float sE[TILE_R * D];  // 64 KB

    const int tid = threadIdx.x;
    const int r0  = blockIdx.x * TILE_R;

    // stage metric: 16384 floats = 4096 float4, 16 per thread, coalesced
    {
        const float4* M4  = (const float4*)M;
        float4*       sM4 = (float4*)sM;
        #pragma unroll
        for (int i = 0; i < (D * D / 4) / 256; ++i)
            sM4[tid + i * 256] = M4[tid + i * 256];
    }
    // stage E tile: TILE_R*128 floats = 4096 float4 (guard partial last tile)
    {
        const float4* E4  = (const float4*)E;
        float4*       sE4 = (float4*)sE;
        #pragma unroll
        for (int i = 0; i < (TILE_R * D / 4) / 256; ++i) {
            int idx = tid + i * 256;
            int row = idx >> 5;                 // 32 float4 per row
            float4 v = make_float4(0.f, 0.f, 0.f, 0.f);
            if (r0 + row < nrows) v = E4[(size_t)r0 * 32 + idx];
            sE4[idx] = v;
        }
    }
    __syncthreads();

    const int cg    = tid & 31;
    const int rg    = tid >> 5;
    const int e0    = cg * 4;
    const int rbase = rg * 16;

    float acc[16][4];
    #pragma unroll
    for (int i = 0; i < 16; ++i) {
        acc[i][0] = 0.f; acc[i][1] = 0.f; acc[i][2] = 0.f; acc[i][3] = 0.f;
    }

    for (int d0 = 0; d0 < D; d0 += 4) {
        // 4 rows of M, 4 consecutive cols each: contiguous b128 reads,
        // lanes 0..31 tile 512B -> conflict-free
        const float4 m0 = *(const float4*)&sM[(d0 + 0) * D + e0];
        const float4 m1 = *(const float4*)&sM[(d0 + 1) * D + e0];
        const float4 m2 = *(const float4*)&sM[(d0 + 2) * D + e0];
        const float4 m3 = *(const float4*)&sM[(d0 + 3) * D + e0];
        #pragma unroll
        for (int i = 0; i < 16; ++i) {
            // broadcast read: all lanes in a half-wave share this address
            const float4 a = *(const float4*)&sE[(rbase + i) * D + d0];
            acc[i][0] += a.x * m0.x + a.y * m1.x + a.z * m2.x + a.w * m3.x;
            acc[i][1] += a.x * m0.y + a.y * m1.y + a.z * m2.y + a.w * m3.y;
            acc[i][2] += a.x * m0.z + a.y * m1.z + a.z * m2.z + a.w * m3.z;
            acc[i][3] += a.x * m0.w + a.y * m1.w + a.z * m2.w + a.w * m3.w;
        }
    }

    #pragma unroll
    for (int i = 0; i < 16; ++i) {
        int row = r0 + rbase + i;
        if (row < nrows) {
            *(float4*)&Eo[(size_t)row * D + e0] =
                make_float4(acc[i][0], acc[i][1], acc[i][2], acc[i][3]);
        }
    }
}

// ---------------------------------------------------------------------------
// Phase 2: out[b] = sigmoid(2 * dot(E'[xs[b]], N[ys[b]]) - 1)
// 16 lanes cooperate per output: each lane reads 2 float4 of each row
// (two coalesced 256B segments per row), shfl_xor tree reduce over 16 lanes.
// Block = 256 threads = 16 outputs.
// ---------------------------------------------------------------------------
__global__ __launch_bounds__(256) void gather_dot(
    const int* __restrict__ xs, const int* __restrict__ ys,
    const float* __restrict__ Ep, const float* __restrict__ Np,
    float* __restrict__ out)
{
    const int tid = threadIdx.x;
    const int o   = blockIdx.x * 16 + (tid >> 4);
    const int l   = tid & 15;

    const int x = xs[o];
    const int y = ys[o];

    const float4* ex = (const float4*)(Ep + (size_t)x * D);
    const float4* ny = (const float4*)(Np + (size_t)y * D);

    const float4 a0 = ex[l];
    const float4 a1 = ex[l + 16];
    const float4 c0 = ny[l];
    const float4 c1 = ny[l + 16];

    float acc = a0.x * c0.x + a0.y * c0.y + a0.z * c0.z + a0.w * c0.w
              + a1.x * c1.x + a1.y * c1.y + a1.z * c1.z + a1.w * c1.w;

    acc += __shfl_xor(acc, 1);
    acc += __shfl_xor(acc, 2);
    acc += __shfl_xor(acc, 4);
    acc += __shfl_xor(acc, 8);

    if (l == 0)
        out[o] = 1.0f / (1.0f + __expf(1.0f - 2.0f * acc));
}

extern "C" void kernel_launch(void* const* d_in, const int* in_sizes, int n_in,
                              void* d_out, int out_size, void* d_ws, size_t ws_size,
                              hipStream_t stream) {
    const int*   xs     = (const int*)d_in[0];
    const int*   ys     = (const int*)d_in[1];
    const float* metric = (const float*)d_in[2];
    const float* EMBEDM = (const float*)d_in[3];
    const float* NEGEM  = (const float*)d_in[4];
    float*       out    = (float*)d_out;
    float*       Ep     = (float*)d_ws;   // 100000*128*4 = 51.2 MB scratch

    const int nrows = in_sizes[3] / D;    // 100000
    const int B     = in_sizes[0];        // 262144

    const int blocks1 = (nrows + TILE_R - 1) / TILE_R;
    precompute_EM<<<blocks1, 256, 0, stream>>>(EMBEDM, metric, Ep, nrows);

    gather_dot<<<B / 16, 256, 0, stream>>>(xs, ys, Ep, NEGEM, out);
}

// Round 2
// 70.084 us; speedup vs baseline: 1.7900x; 1.7900x over previous
//
#include <hip/hip_runtime.h>
#include <hip/hip_bf16.h>

#define D 128
#define TILE_R 128   // rows per block in the MFMA precompute GEMM

typedef __attribute__((ext_vector_type(8))) __bf16 bf16x8;
typedef __attribute__((ext_vector_type(4))) float  f32x4;

union FragU { unsigned short s[8]; bf16x8 v; };

// Split fp32 -> bf16 hi/lo by truncation: f ~= hi + lo with |residual| ~ 2^-16 |f|.
__device__ inline void split8(const float* f, FragU& h, FragU& l) {
    #pragma unroll
    for (int j = 0; j < 8; ++j) {
        unsigned u = __float_as_uint(f[j]);
        h.s[j] = (unsigned short)(u >> 16);
        float hf = __uint_as_float(u & 0xFFFF0000u);
        l.s[j] = (unsigned short)(__float_as_uint(f[j] - hf) >> 16);
    }
}

// ---------------------------------------------------------------------------
// Kernel 0: convert metric -> fragment-ordered bf16 hi/lo B-fragments.
// Output layout: chunk q = (kk*8+cf)*64 + lane holds B[k0..k0+7][col] where
// col = cf*16 + (lane&15), k0 = kk*32 + (lane>>4)*8. 8 blocks x 256 thr.
// Stored in d_out (64 KB scratch), fully overwritten later by gather_dot.
// ---------------------------------------------------------------------------
__global__ __launch_bounds__(256) void convert_M(
    const float* __restrict__ M,
    unsigned short* __restrict__ mh, unsigned short* __restrict__ ml)
{
    const int q    = blockIdx.x * 256 + threadIdx.x;  // [0, 2048)
    const int kk   = q >> 9;
    const int cf   = (q >> 6) & 7;
    const int lane = q & 63;
    const int col  = cf * 16 + (lane & 15);
    const int k0   = kk * 32 + (lane >> 4) * 8;

    float f[8];
    #pragma unroll
    for (int j = 0; j < 8; ++j) f[j] = M[(k0 + j) * D + col];

    FragU h, l;
    split8(f, h, l);
    #pragma unroll
    for (int j = 0; j < 8; ++j) { mh[q * 8 + j] = h.s[j]; ml[q * 8 + j] = l.s[j]; }
}

// ---------------------------------------------------------------------------
// Phase 1: E' = EMBEDM @ metric via split-bf16 MFMA (3 terms).
// Block = 256 thr = 4 waves; wave w owns rows [blk*128 + w*32, +32) x all 128 cols.
// No LDS: A-fragments loaded directly from global fp32 (wave reads 16 rows x
// 128B contiguous per kk -> fully consumed cache lines) and split in-register.
// B-fragments: perfectly coalesced 1KB/instr loads from the fragment-ordered
// bf16 buffers (L2-hot, identical across blocks).
// acc[2][8] = 64 VGPR, B-frags 64, A-frags 16 -> ~2 blocks/CU.
// ---------------------------------------------------------------------------
__global__ __launch_bounds__(256, 2) void precompute_EM_mfma(
    const float* __restrict__ E,
    const unsigned short* __restrict__ mh, const unsigned short* __restrict__ ml,
    float* __restrict__ Eo, int nrows)
{
    const int tid   = threadIdx.x;
    const int lane  = tid & 63;
    const int wid   = tid >> 6;
    const int rows0 = blockIdx.x * TILE_R + wid * 32;
    const int lrow  = lane & 15;
    const int lk    = lane >> 4;   // 0..3

    f32x4 acc[2][8];
    #pragma unroll
    for (int rf = 0; rf < 2; ++rf)
        #pragma unroll
        for (int cf = 0; cf < 8; ++cf)
            acc[rf][cf] = (f32x4){0.f, 0.f, 0.f, 0.f};

    for (int kk = 0; kk < 4; ++kk) {
        // B fragments (16 x dwordx4, contiguous 1KB per wave-instruction)
        FragU bh[8], bl[8];
        #pragma unroll
        for (int cf = 0; cf < 8; ++cf) {
            const int off = ((kk * 8 + cf) * 64 + lane) * 8;
            bh[cf].v = *(const bf16x8*)(mh + off);
            bl[cf].v = *(const bf16x8*)(ml + off);
        }

        // A fragments: row = rows0 + rf*16 + (lane&15), k = kk*32 + lk*8 .. +7
        FragU ah[2], al[2];
        #pragma unroll
        for (int rf = 0; rf < 2; ++rf) {
            const int row = rows0 + rf * 16 + lrow;
            float f[8];
            if (row < nrows) {
                const f32x4* p = (const f32x4*)(E + (size_t)row * D + kk * 32 + lk * 8);
                f32x4 a = p[0], b = p[1];
                f[0] = a.x; f[1] = a.y; f[2] = a.z; f[3] = a.w;
                f[4] = b.x; f[5] = b.y; f[6] = b.z; f[7] = b.w;
            } else {
                #pragma unroll
                for (int j = 0; j < 8; ++j) f[j] = 0.f;
            }
            split8(f, ah[rf], al[rf]);
        }

        // 3-term split accumulate: Eh@Mh + Eh@Ml + El@Mh
        #pragma unroll
        for (int rf = 0; rf < 2; ++rf) {
            #pragma unroll
            for (int cf = 0; cf < 8; ++cf) {
                acc[rf][cf] = __builtin_amdgcn_mfma_f32_16x16x32_bf16(
                    ah[rf].v, bh[cf].v, acc[rf][cf], 0, 0, 0);
                acc[rf][cf] = __builtin_amdgcn_mfma_f32_16x16x32_bf16(
                    ah[rf].v, bl[cf].v, acc[rf][cf], 0, 0, 0);
                acc[rf][cf] = __builtin_amdgcn_mfma_f32_16x16x32_bf16(
                    al[rf].v, bh[cf].v, acc[rf][cf], 0, 0, 0);
            }
        }
    }

    // C/D layout (m89-verified): col = lane&15, row = (lane>>4)*4 + i
    #pragma unroll
    for (int rf = 0; rf < 2; ++rf) {
        #pragma unroll
        for (int cf = 0; cf < 8; ++cf) {
            #pragma unroll
            for (int i = 0; i < 4; ++i) {
                const int row = rows0 + rf * 16 + lk * 4 + i;
                const int col = cf * 16 + lrow;
                if (row < nrows) Eo[(size_t)row * D + col] = acc[rf][cf][i];
            }
        }
    }
}

// ---------------------------------------------------------------------------
// Phase 2: out[b] = sigmoid(2 * dot(E'[xs[b]], N[ys[b]]) - 1)
// 16 lanes per output, coalesced 256B row segments, shfl_xor reduce.
// ---------------------------------------------------------------------------
__global__ __launch_bounds__(256) void gather_dot(
    const int* __restrict__ xs, const int* __restrict__ ys,
    const float* __restrict__ Ep, const float* __restrict__ Np,
    float* __restrict__ out)
{
    const int tid = threadIdx.x;
    const int o   = blockIdx.x * 16 + (tid >> 4);
    const int l   = tid & 15;

    const int x = xs[o];
    const int y = ys[o];

    const float4* ex = (const float4*)(Ep + (size_t)x * D);
    const float4* ny = (const float4*)(Np + (size_t)y * D);

    const float4 a0 = ex[l];
    const float4 a1 = ex[l + 16];
    const float4 c0 = ny[l];
    const float4 c1 = ny[l + 16];

    float acc = a0.x * c0.x + a0.y * c0.y + a0.z * c0.z + a0.w * c0.w
              + a1.x * c1.x + a1.y * c1.y + a1.z * c1.z + a1.w * c1.w;

    acc += __shfl_xor(acc, 1);
    acc += __shfl_xor(acc, 2);
    acc += __shfl_xor(acc, 4);
    acc += __shfl_xor(acc, 8);

    if (l == 0)
        out[o] = 1.0f / (1.0f + __expf(1.0f - 2.0f * acc));
}

extern "C" void kernel_launch(void* const* d_in, const int* in_sizes, int n_in,
                              void* d_out, int out_size, void* d_ws, size_t ws_size,
                              hipStream_t stream) {
    const int*   xs     = (const int*)d_in[0];
    const int*   ys     = (const int*)d_in[1];
    const float* metric = (const float*)d_in[2];
    const float* EMBEDM = (const float*)d_in[3];
    const float* NEGEM  = (const float*)d_in[4];
    float*       out    = (float*)d_out;
    float*       Ep     = (float*)d_ws;   // 100000*128*4 = 51.2 MB scratch

    const int nrows = in_sizes[3] / D;    // 100000
    const int B     = in_sizes[0];        // 262144

    // M bf16 hi/lo fragment buffers live in the first 64 KB of d_out (1 MB);
    // gather_dot fully overwrites d_out afterwards.
    unsigned short* mh = (unsigned short*)d_out;          // 32 KB
    unsigned short* ml = (unsigned short*)d_out + 16384;  // 32 KB

    convert_M<<<8, 256, 0, stream>>>(metric, mh, ml);

    const int blocks1 = (nrows + TILE_R - 1) / TILE_R;
    precompute_EM_mfma<<<blocks1, 256, 0, stream>>>(EMBEDM, mh, ml, Ep, nrows);

    gather_dot<<<B / 16, 256, 0, stream>>>(xs, ys, Ep, NEGEM, out);
}

// Round 3
// 56.561 us; speedup vs baseline: 2.2180x; 1.2391x over previous
//
#include <hip/hip_runtime.h>
#include <hip/hip_bf16.h>
#include <hip/hip_fp16.h>

#define D 128
#define TILE_R 128   // rows per block in the MFMA precompute GEMM

typedef __attribute__((ext_vector_type(8))) __bf16   bf16x8;
typedef __attribute__((ext_vector_type(4))) float    f32x4;
typedef __attribute__((ext_vector_type(8))) _Float16 f16x8;

union FragU { unsigned short s[8]; bf16x8 v; };

// Split fp32 -> bf16 hi/lo by truncation: f ~= hi + lo, |residual| ~ 2^-16 |f|.
__device__ inline void split8(const float* f, FragU& h, FragU& l) {
    #pragma unroll
    for (int j = 0; j < 8; ++j) {
        unsigned u = __float_as_uint(f[j]);
        h.s[j] = (unsigned short)(u >> 16);
        float hf = __uint_as_float(u & 0xFFFF0000u);
        l.s[j] = (unsigned short)(__float_as_uint(f[j] - hf) >> 16);
    }
}

// ---------------------------------------------------------------------------
// Kernel 0: metric -> fragment-ordered bf16 hi/lo B-fragments (in d_ws).
// ---------------------------------------------------------------------------
__global__ __launch_bounds__(256) void convert_M(
    const float* __restrict__ M,
    unsigned short* __restrict__ mh, unsigned short* __restrict__ ml)
{
    const int q    = blockIdx.x * 256 + threadIdx.x;  // [0, 2048)
    const int kk   = q >> 9;
    const int cf   = (q >> 6) & 7;
    const int lane = q & 63;
    const int col  = cf * 16 + (lane & 15);
    const int k0   = kk * 32 + (lane >> 4) * 8;

    float f[8];
    #pragma unroll
    for (int j = 0; j < 8; ++j) f[j] = M[(k0 + j) * D + col];

    FragU h, l;
    split8(f, h, l);
    #pragma unroll
    for (int j = 0; j < 8; ++j) { mh[q * 8 + j] = h.s[j]; ml[q * 8 + j] = l.s[j]; }
}

// ---------------------------------------------------------------------------
// Kernel 1 (fused): blocks [0,nblkE): E' = E @ M via split-bf16 MFMA, output
// stored fp16 in pi-permuted column order pi(col) = (col&15)*8 + (col>>4)
// (dot in gather is order-invariant; pi makes the epilogue's per-thread 8
// cf-values contiguous -> 16B stores). Blocks [nblkE, ...): convert N to fp16
// in the SAME pi order (16 rows/block, lane reads stride-16 cols, writes 16B).
// ---------------------------------------------------------------------------
__global__ __launch_bounds__(256) void fused_prep(
    const float* __restrict__ E, const float* __restrict__ N,
    const unsigned short* __restrict__ mh, const unsigned short* __restrict__ ml,
    _Float16* __restrict__ Ep16, _Float16* __restrict__ Np16,
    int nrows, int nblkE)
{
    const int tid = threadIdx.x;

    if ((int)blockIdx.x >= nblkE) {
        // ---- N-convert path ----
        const int nb  = blockIdx.x - nblkE;
        const int l16 = tid & 15;
        const int row = nb * 16 + (tid >> 4);
        if (row < nrows) {
            f16x8 h;
            #pragma unroll
            for (int k = 0; k < 8; ++k)
                h[k] = (_Float16)N[(size_t)row * D + l16 + 16 * k];
            *(f16x8*)(Np16 + (size_t)row * D + l16 * 8) = h;
        }
        return;
    }

    // ---- E-path: MFMA GEMM ----
    const int lane  = tid & 63;
    const int wid   = tid >> 6;
    const int rows0 = blockIdx.x * TILE_R + wid * 32;
    const int lrow  = lane & 15;
    const int lk    = lane >> 4;   // 0..3

    f32x4 acc[2][8];
    #pragma unroll
    for (int rf = 0; rf < 2; ++rf)
        #pragma unroll
        for (int cf = 0; cf < 8; ++cf)
            acc[rf][cf] = (f32x4){0.f, 0.f, 0.f, 0.f};

    for (int kk = 0; kk < 4; ++kk) {
        FragU bh[8], bl[8];
        #pragma unroll
        for (int cf = 0; cf < 8; ++cf) {
            const int off = ((kk * 8 + cf) * 64 + lane) * 8;
            bh[cf].v = *(const bf16x8*)(mh + off);
            bl[cf].v = *(const bf16x8*)(ml + off);
        }

        FragU ah[2], al[2];
        #pragma unroll
        for (int rf = 0; rf < 2; ++rf) {
            const int row = rows0 + rf * 16 + lrow;
            float f[8];
            if (row < nrows) {
                const f32x4* p = (const f32x4*)(E + (size_t)row * D + kk * 32 + lk * 8);
                f32x4 a = p[0], b = p[1];
                f[0] = a.x; f[1] = a.y; f[2] = a.z; f[3] = a.w;
                f[4] = b.x; f[5] = b.y; f[6] = b.z; f[7] = b.w;
            } else {
                #pragma unroll
                for (int j = 0; j < 8; ++j) f[j] = 0.f;
            }
            split8(f, ah[rf], al[rf]);
        }

        #pragma unroll
        for (int rf = 0; rf < 2; ++rf) {
            #pragma unroll
            for (int cf = 0; cf < 8; ++cf) {
                acc[rf][cf] = __builtin_amdgcn_mfma_f32_16x16x32_bf16(
                    ah[rf].v, bh[cf].v, acc[rf][cf], 0, 0, 0);
                acc[rf][cf] = __builtin_amdgcn_mfma_f32_16x16x32_bf16(
                    ah[rf].v, bl[cf].v, acc[rf][cf], 0, 0, 0);
                acc[rf][cf] = __builtin_amdgcn_mfma_f32_16x16x32_bf16(
                    al[rf].v, bh[cf].v, acc[rf][cf], 0, 0, 0);
            }
        }
    }

    // Epilogue: C/D layout col=lane&15, row=(lane>>4)*4+i (m89-verified).
    // pi(cf*16 + lrow) = lrow*8 + cf -> per-(rf,i) 8 cf-values contiguous.
    #pragma unroll
    for (int rf = 0; rf < 2; ++rf) {
        #pragma unroll
        for (int i = 0; i < 4; ++i) {
            const int row = rows0 + rf * 16 + lk * 4 + i;
            if (row < nrows) {
                f16x8 h;
                #pragma unroll
                for (int cf = 0; cf < 8; ++cf) h[cf] = (_Float16)acc[rf][cf][i];
                *(f16x8*)(Ep16 + (size_t)row * D + lrow * 8) = h;
            }
        }
    }
}

// ---------------------------------------------------------------------------
// Kernel 2: out[b] = sigmoid(2 * dot16(Ep16[xs[b]], Np16[ys[b]]) - 1).
// 16 lanes per output, 2 outputs per lane-group (4 x 16B loads in flight),
// rows are 256B fp16 -> one dwordx4 per table per output. fp32 accumulate.
// ---------------------------------------------------------------------------
__global__ __launch_bounds__(256) void gather_dot16(
    const int* __restrict__ xs, const int* __restrict__ ys,
    const _Float16* __restrict__ Ep16, const _Float16* __restrict__ Np16,
    float* __restrict__ out)
{
    const int tid = threadIdx.x;
    const int o0  = blockIdx.x * 32 + (tid >> 4) * 2;
    const int l   = tid & 15;

    const int x0 = xs[o0], x1 = xs[o0 + 1];
    const int y0 = ys[o0], y1 = ys[o0 + 1];

    const f16x8 a0 = *(const f16x8*)(Ep16 + (size_t)x0 * D + l * 8);
    const f16x8 b0 = *(const f16x8*)(Np16 + (size_t)y0 * D + l * 8);
    const f16x8 a1 = *(const f16x8*)(Ep16 + (size_t)x1 * D + l * 8);
    const f16x8 b1 = *(const f16x8*)(Np16 + (size_t)y1 * D + l * 8);

    float r0 = 0.f, r1 = 0.f;
    #pragma unroll
    for (int j = 0; j < 8; ++j) {
        r0 += (float)a0[j] * (float)b0[j];
        r1 += (float)a1[j] * (float)b1[j];
    }

    r0 += __shfl_xor(r0, 1); r1 += __shfl_xor(r1, 1);
    r0 += __shfl_xor(r0, 2); r1 += __shfl_xor(r1, 2);
    r0 += __shfl_xor(r0, 4); r1 += __shfl_xor(r1, 4);
    r0 += __shfl_xor(r0, 8); r1 += __shfl_xor(r1, 8);

    if (l == 0) {
        float2 v;
        v.x = 1.0f / (1.0f + __expf(1.0f - 2.0f * r0));
        v.y = 1.0f / (1.0f + __expf(1.0f - 2.0f * r1));
        *(float2*)(out + o0) = v;
    }
}

extern "C" void kernel_launch(void* const* d_in, const int* in_sizes, int n_in,
                              void* d_out, int out_size, void* d_ws, size_t ws_size,
                              hipStream_t stream) {
    const int*   xs     = (const int*)d_in[0];
    const int*   ys     = (const int*)d_in[1];
    const float* metric = (const float*)d_in[2];
    const float* EMBEDM = (const float*)d_in[3];
    const float* NEGEM  = (const float*)d_in[4];
    float*       out    = (float*)d_out;

    const int nrows = in_sizes[3] / D;    // 100000
    const int B     = in_sizes[0];        // 262144

    // d_ws layout (ws >= 256 MiB per harness fill): Ep16 25.6MB @0,
    // Np16 25.6MB @32MB, M-fragments 64KB @64MB.
    char* ws = (char*)d_ws;
    _Float16*       Ep16 = (_Float16*)ws;
    _Float16*       Np16 = (_Float16*)(ws + (32u << 20));
    unsigned short* mh   = (unsigned short*)(ws + (64u << 20));
    unsigned short* ml   = (unsigned short*)(ws + (64u << 20) + (32u << 10));

    convert_M<<<8, 256, 0, stream>>>(metric, mh, ml);

    const int nblkE = (nrows + TILE_R - 1) / TILE_R;       // 782
    const int nblkN = (nrows + 15) / 16;                   // 6250
    fused_prep<<<nblkE + nblkN, 256, 0, stream>>>(EMBEDM, NEGEM, mh, ml,
                                                  Ep16, Np16, nrows, nblkE);

    gather_dot16<<<B / 32, 256, 0, stream>>>(xs, ys, Ep16, Np16, out);
}